// Round 4
// baseline (99.047 us; speedup 1.0000x reference)
//
#include <hip/hip_runtime.h>
#include <hip/hip_bf16.h>

#define HH 224
#define WW 224
#define HWPIX (HH * WW)          // 50176 = 196 * 256
#define BLOCKS_PER_IMG 196
#define NXCD 8

typedef float f2 __attribute__((ext_vector_type(2), aligned(4)));
typedef float f3 __attribute__((ext_vector_type(3), aligned(4)));
typedef float f4 __attribute__((ext_vector_type(4), aligned(4)));
typedef _Float16 h4 __attribute__((ext_vector_type(4), aligned(8)));
typedef _Float16 h8 __attribute__((ext_vector_type(8), aligned(8)));

// ---------- prepass: x (5 x f32 / px) -> packed f16 RGBX (8B/px) + f2 coords ----------
__global__ __launch_bounds__(256) void Bilinear_prepass(
    const float* __restrict__ x, h4* __restrict__ wimg, f2* __restrict__ wxy, int total) {
    int i = blockIdx.x * 256 + threadIdx.x;
    if (i >= total) return;
    const float* p = x + (size_t)i * 5;
    f3 c  = *(const f3*)p;          // dwordx3: r,g,b
    f2 xy = *(const f2*)(p + 3);    // dwordx2: X,Y
    h4 h;
    h.x = (_Float16)c.x; h.y = (_Float16)c.y; h.z = (_Float16)c.z; h.w = (_Float16)0.f;
    wimg[i] = h;                    // dense 8B store
    wxy[i]  = xy;                   // dense 8B store
}

// ---------- main: 2 aligned dwordx4 gathers per pixel (tl+tr fused, bl+br fused) ----------
__global__ __launch_bounds__(256) void Bilinear_48232482734312_kernel(
    const h4* __restrict__ wimg, const f2* __restrict__ wxy,
    float* __restrict__ out, int n_img) {
    // XCD-aware swizzle: each image's 196 blocks on ONE XCD -> 401KB panel L2-resident.
    int wg = blockIdx.x;
    int xcd = wg & (NXCD - 1);
    int slot = wg >> 3;
    int img_group = slot / BLOCKS_PER_IMG;
    int blk = slot - img_group * BLOCKS_PER_IMG;
    int img = img_group * NXCD + xcd;
    if (img >= n_img) return;

    size_t idx = (size_t)img * HWPIX + blk * 256 + threadIdx.x;

    f2 xy = wxy[idx];
    float X = xy.x, Y = xy.y;
    float fx = floorf(X), fy = floorf(Y);
    float wx = X - fx, wy = Y - fy;

    int x0 = min(max((int)fx,     0), WW - 1);
    int x1 = min(max((int)fx + 1, 0), WW - 1);
    int y0 = min(max((int)fy,     0), HH - 1);
    int y1 = min(max((int)fy + 1, 0), HH - 1);

    const h4* base = wimg + (size_t)img * HWPIX;
    // 16B load covers pixels (y,x0) and (y,x0+1); 8B-aligned, never crosses when x1==x0+1.
    h8 top = *(const h8*)(base + ((size_t)y0 * WW + x0));
    h8 bot = *(const h8*)(base + ((size_t)y1 * WW + x0));

    bool dup = (x1 == x0);  // only reachable if clamp fires (X>=223); real inputs: never
    float tl0 = (float)top[0], tl1 = (float)top[1], tl2 = (float)top[2];
    float bl0 = (float)bot[0], bl1 = (float)bot[1], bl2 = (float)bot[2];
    float tr0 = dup ? tl0 : (float)top[4];
    float tr1 = dup ? tl1 : (float)top[5];
    float tr2 = dup ? tl2 : (float)top[6];
    float br0 = dup ? bl0 : (float)bot[4];
    float br1 = dup ? bl1 : (float)bot[5];
    float br2 = dup ? bl2 : (float)bot[6];

    float wtl = (1.0f - wx) * (1.0f - wy);
    float wbl = (1.0f - wx) * wy;
    float wtr = wx * (1.0f - wy);
    float wbr = wx * wy;

    float o0 = wtl * tl0 + wbl * bl0 + wtr * tr0 + wbr * br0;
    float o1 = wtl * tl1 + wbl * bl1 + wtr * tr1 + wbr * br1;
    float o2 = wtl * tl2 + wbl * bl2 + wtr * tr2 + wbr * br2;

    float* o = out + idx * 3;
    *(f2*)o = (f2){o0, o1};
    o[2] = o2;
}

// ---------- fallback (R3 kernel) if ws_size is too small ----------
__global__ __launch_bounds__(256) void Bilinear_fallback(
    const float* __restrict__ x, float* __restrict__ out, int n_img) {
    int wg = blockIdx.x;
    int xcd = wg & (NXCD - 1);
    int slot = wg >> 3;
    int img_group = slot / BLOCKS_PER_IMG;
    int blk = slot - img_group * BLOCKS_PER_IMG;
    int img = img_group * NXCD + xcd;
    if (img >= n_img) return;

    size_t idx = (size_t)img * HWPIX + blk * 256 + threadIdx.x;
    f2 xy = *(const f2*)(x + idx * 5 + 3);
    float X = xy.x, Y = xy.y;
    float fx = floorf(X), fy = floorf(Y);
    float wx = X - fx, wy = Y - fy;
    int x0 = min(max((int)fx,     0), WW - 1);
    int x1 = min(max((int)fx + 1, 0), WW - 1);
    int y0 = min(max((int)fy,     0), HH - 1);
    int y1 = min(max((int)fy + 1, 0), HH - 1);
    const float* imgb = x + (size_t)img * HWPIX * 5;
    const float* r0 = imgb + (size_t)y0 * (WW * 5);
    const float* r1 = imgb + (size_t)y1 * (WW * 5);
    f4 tl = *(const f4*)(r0 + x0 * 5);
    f4 tr = *(const f4*)(r0 + x1 * 5);
    f4 bl = *(const f4*)(r1 + x0 * 5);
    f4 br = *(const f4*)(r1 + x1 * 5);
    float wtl = (1.0f - wx) * (1.0f - wy);
    float wbl = (1.0f - wx) * wy;
    float wtr = wx * (1.0f - wy);
    float wbr = wx * wy;
    float o0 = wtl * tl.x + wbl * bl.x + wtr * tr.x + wbr * br.x;
    float o1 = wtl * tl.y + wbl * bl.y + wtr * tr.y + wbr * br.y;
    float o2 = wtl * tl.z + wbl * bl.z + wtr * tr.z + wbr * br.z;
    float* o = out + idx * 3;
    *(f2*)o = (f2){o0, o1};
    o[2] = o2;
}

extern "C" void kernel_launch(void* const* d_in, const int* in_sizes, int n_in,
                              void* d_out, int out_size, void* d_ws, size_t ws_size,
                              hipStream_t stream) {
    const float* x = (const float*)d_in[0];
    float* out = (float*)d_out;
    int total = in_sizes[0] / 5;           // B*H*W pixels
    int n_img = total / HWPIX;             // 128
    int n_img_pad = (n_img + NXCD - 1) & ~(NXCD - 1);
    int grid_main = n_img_pad * BLOCKS_PER_IMG;

    size_t need = (size_t)total * 8 /*wimg*/ + (size_t)total * 8 /*wxy*/;
    if (ws_size >= need) {
        h4* wimg = (h4*)d_ws;
        f2* wxy  = (f2*)((char*)d_ws + (size_t)total * 8);
        int grid_pre = (total + 255) / 256;
        Bilinear_prepass<<<grid_pre, 256, 0, stream>>>(x, wimg, wxy, total);
        Bilinear_48232482734312_kernel<<<grid_main, 256, 0, stream>>>(wimg, wxy, out, n_img);
    } else {
        Bilinear_fallback<<<grid_main, 256, 0, stream>>>(x, out, n_img);
    }
}